// Round 13
// baseline (1176.765 us; speedup 1.0000x reference)
//
#include <hip/hip_runtime.h>

using u16 = unsigned short;
using u32 = unsigned int;
typedef int i32x4 __attribute__((ext_vector_type(4)));
typedef int i32x8 __attribute__((ext_vector_type(8)));
typedef float f32x4 __attribute__((ext_vector_type(4)));
typedef float f32x2 __attribute__((ext_vector_type(2)));
typedef float f32x16 __attribute__((ext_vector_type(16)));

#define SC1 0x7F7F7F7F  // e8m0 scale bytes = 2^0 = 1.0 (exact)

// ---------------------------------------------------------------------------
__device__ inline void async16(const void* g, void* l) {
    __builtin_amdgcn_global_load_lds(
        (__attribute__((address_space(1))) void*)(g),
        (__attribute__((address_space(3))) void*)(l),
        16, 0, 0);
}

__device__ inline i32x8 mk8(i32x4 lo, i32x4 hi) {
    return __builtin_shufflevector(lo, hi, 0, 1, 2, 3, 4, 5, 6, 7);
}

// ---------------------------------------------------------------------------
// Fused quantize, 2 blocks per wave (float4/lane): per-128-block
// s = amax * (1/448) (== amax/448 within 1 ulp), payload fp8 e4m3fn RNE of
// x * (448/amax). fp8 [R][K]; scales [K/128][R].
__global__ void quant_kernel(const float* __restrict__ x,
                             const float* __restrict__ w,
                             u32* __restrict__ Aq, u32* __restrict__ Bq,
                             float* __restrict__ Asc, float* __restrict__ Bsc,
                             long nA, long nTot, long MM, long NN) {
    long wv = (long)blockIdx.x * 4 + (threadIdx.x >> 6);
    int lane = threadIdx.x & 63;
    long b0 = wv * 2;
    if (b0 >= nTot) return;

    const float* in; u32* outq; float* outs; long R, id0;
    if (b0 < nA) { in = x; outq = Aq; outs = Asc; R = MM; id0 = b0; }
    else         { in = w; outq = Bq; outs = Bsc; R = NN; id0 = b0 - nA; }

    float4 v = reinterpret_cast<const float4*>(in)[id0 * 32 + lane];
    float a = fmaxf(fmaxf(fabsf(v.x), fabsf(v.y)), fmaxf(fabsf(v.z), fabsf(v.w)));
#pragma unroll
    for (int off = 16; off; off >>= 1) a = fmaxf(a, __shfl_xor(a, off));

    float s = a * (1.0f / 448.0f);
    float inv = 448.0f / a;

    float q0 = fminf(fmaxf(v.x * inv, -448.0f), 448.0f);
    float q1 = fminf(fmaxf(v.y * inv, -448.0f), 448.0f);
    float q2 = fminf(fmaxf(v.z * inv, -448.0f), 448.0f);
    float q3 = fminf(fmaxf(v.w * inv, -448.0f), 448.0f);

    int pk = __builtin_amdgcn_cvt_pk_fp8_f32(q0, q1, 0, false);
    pk = __builtin_amdgcn_cvt_pk_fp8_f32(q2, q3, pk, true);
    outq[id0 * 32 + lane] = (u32)pk;

    if ((lane & 31) == 0) {
        long b = id0 + (lane >> 5);
        outs[(b & 31) * R + (b >> 5)] = s;
    }
}

// ---------------------------------------------------------------------------
// fp8 block-scaled GEMM, 128x128 tile, 4 waves (2x2, wave tile 64x64),
// slab = K-block of 128. mfma_scale_f32_32x32x64_f8f6f4, HW scale 1.0;
// fp32 per-slab packed rescale (reference math, fp32 accumulate).
// SINGLE-buffered LDS (33.8KB) -> 4 blocks/CU (16 waves/CU): the per-slab
// vmcnt(0) drain hides behind THREE sibling blocks' compute (m114 TLP), vs
// one with the 66KB double-buffer (R9/R12 = 198us). Loop per slab:
//   STAGE(kb) -> vmcnt(0)+barrier -> reads+compute -> barrier (WAR guard).
// LDS: A 16KB @0, B 16KB @16K, sa 512B @32K, sb 512B @32.5K.
// Swizzle byte^=(row&7)<<4 both-sides (128B rows, verified R6/R9).

#define SWZ(x) ((x) ^ ((((x) >> 7) & 7) << 4))

#define FENCE asm volatile("" ::: "memory");
#define BARRIER { __builtin_amdgcn_s_barrier(); FENCE }
#define VMC0 { asm volatile("s_waitcnt vmcnt(0)" ::: "memory"); }

__global__ __launch_bounds__(256, 4) void gemm_fp8(
    const char* __restrict__ Aq, const char* __restrict__ Bq,
    const float* __restrict__ AscaleG, const float* __restrict__ BscaleG,
    float* __restrict__ C, int M, int N) {
    extern __shared__ __align__(16) char smem[];
    const int KBYTES = 4096;

    const int tid = threadIdx.x;
    const int wid = tid >> 6;
    const int lane = tid & 63;
    const int l31 = lane & 31;
    const int lh = lane >> 5;
    const int wr2 = wid >> 1;          // 0..1 (M half)
    const int wc2 = wid & 1;           // 0..1 (N half)

    int nwg = gridDim.x, bid = blockIdx.x, swz = bid;
    if ((nwg & 7) == 0) swz = (bid & 7) * (nwg >> 3) + (bid >> 3);
    const int nbn = N >> 7;            // 32
    const long brow = (long)(swz / nbn) << 7;
    const long bcol = (long)(swz % nbn) << 7;

    const char* Abase = Aq + brow * KBYTES;
    const char* Bbase = Bq + bcol * KBYTES;

    // staging source offsets (inverse-swizzled); dloc = c*4096 + tid*16
    int aofs[4];
#pragma unroll
    for (int c = 0; c < 4; ++c) {
        int dloc = c * 4096 + tid * 16;
        int l = SWZ(dloc);
        aofs[c] = (l >> 7) * KBYTES + (l & 127);
    }

    // swizzled fragment column offsets (row&7 == lane&7 for all our rows)
    int cox[4];
#pragma unroll
    for (int kh = 0; kh < 2; ++kh)
#pragma unroll
        for (int hh = 0; hh < 2; ++hh)
            cox[kh * 2 + hh] =
                (((kh << 6) | (lh << 5) | (hh << 4)) ^ ((lane & 7) << 4));

    int arowb[2], brownn[2];
#pragma unroll
    for (int rb = 0; rb < 2; ++rb) arowb[rb] = (wr2 * 64 + rb * 32 + l31) << 7;
#pragma unroll
    for (int n = 0; n < 2; ++n) brownn[n] = (wc2 * 64 + n * 32 + l31) << 7;

#define STAGE(kb1) { \
    _Pragma("unroll") for (int c_ = 0; c_ < 4; ++c_) { \
        char* dA_ = smem + c_ * 4096 + wid * 1024; \
        async16(Abase + aofs[c_] + (long)(kb1) * 128, dA_); \
        async16(Bbase + aofs[c_] + (long)(kb1) * 128, dA_ + 16384); } \
    if (wid == 0 && lane < 32) \
        async16((const char*)AscaleG + ((long)(kb1) * M + brow) * 4 + lane * 16, \
                smem + 32768); \
    if (wid == 1 && lane < 32) \
        async16((const char*)BscaleG + ((long)(kb1) * N + bcol) * 4 + lane * 16, \
                smem + 33280); }

    f32x4 acc[2][2][4];
#pragma unroll
    for (int rb = 0; rb < 2; ++rb)
#pragma unroll
        for (int n = 0; n < 2; ++n)
#pragma unroll
            for (int i = 0; i < 4; ++i) acc[rb][n][i] = (f32x4){0.f, 0.f, 0.f, 0.f};

    const char* Ab = smem;
    const char* Bb = smem + 16384;
    const float* Sa = (const float*)(smem + 32768);
    const float* Sb = (const float*)(smem + 33280);

    for (int kb = 0; kb < 32; ++kb) {
        STAGE(kb);
        VMC0; BARRIER;

        i32x8 bfr[2][2];  // [n][kh]
#pragma unroll
        for (int n = 0; n < 2; ++n)
#pragma unroll
            for (int kh = 0; kh < 2; ++kh)
                bfr[n][kh] = mk8(*(const i32x4*)(Bb + brownn[n] + cox[kh * 2]),
                                 *(const i32x4*)(Bb + brownn[n] + cox[kh * 2 + 1]));
        float sbv[2];
#pragma unroll
        for (int n = 0; n < 2; ++n) sbv[n] = Sb[wc2 * 64 + n * 32 + l31];

#pragma unroll
        for (int rb = 0; rb < 2; ++rb) {
            i32x8 a0 = mk8(*(const i32x4*)(Ab + arowb[rb] + cox[0]),
                           *(const i32x4*)(Ab + arowb[rb] + cox[1]));
            i32x8 a1 = mk8(*(const i32x4*)(Ab + arowb[rb] + cox[2]),
                           *(const i32x4*)(Ab + arowb[rb] + cox[3]));
            f32x4 sa4[4];
#pragma unroll
            for (int i = 0; i < 4; ++i)
                sa4[i] = *(const f32x4*)(Sa + wr2 * 64 + rb * 32 + 4 * lh + 8 * i);
            __builtin_amdgcn_s_setprio(1);
            f32x16 t0 = __builtin_amdgcn_mfma_scale_f32_32x32x64_f8f6f4(
                a0, bfr[0][0], (f32x16)(0.f), 0, 0, 0, SC1, 0, SC1);
            t0 = __builtin_amdgcn_mfma_scale_f32_32x32x64_f8f6f4(
                a1, bfr[0][1], t0, 0, 0, 0, SC1, 0, SC1);
            f32x16 t1 = __builtin_amdgcn_mfma_scale_f32_32x32x64_f8f6f4(
                a0, bfr[1][0], (f32x16)(0.f), 0, 0, 0, SC1, 0, SC1);
            t1 = __builtin_amdgcn_mfma_scale_f32_32x32x64_f8f6f4(
                a1, bfr[1][1], t1, 0, 0, 0, SC1, 0, SC1);
            __builtin_amdgcn_s_setprio(0);
            // packed rescale: f32x4 -> v_pk_mul_f32 / v_pk_fma_f32
#pragma unroll
            for (int i = 0; i < 4; ++i) {
                f32x4 sp0 = sa4[i] * sbv[0];
                f32x4 sp1 = sa4[i] * sbv[1];
                f32x4 tv0 = (f32x4){t0[i * 4], t0[i * 4 + 1],
                                    t0[i * 4 + 2], t0[i * 4 + 3]};
                f32x4 tv1 = (f32x4){t1[i * 4], t1[i * 4 + 1],
                                    t1[i * 4 + 2], t1[i * 4 + 3]};
                acc[rb][0][i] = tv0 * sp0 + acc[rb][0][i];
                acc[rb][1][i] = tv1 * sp1 + acc[rb][1][i];
            }
        }

        BARRIER;  // WAR guard: all waves done reading before next STAGE
    }

    // epilogue: 32x32 C/D layout col = lane&31, row = (e&3)+8*(e>>2)+4*lh
#pragma unroll
    for (int rb = 0; rb < 2; ++rb)
#pragma unroll
        for (int n = 0; n < 2; ++n)
#pragma unroll
            for (int i = 0; i < 4; ++i)
#pragma unroll
                for (int j = 0; j < 4; ++j) {
                    long r = brow + wr2 * 64 + rb * 32 + j + 8 * i + 4 * lh;
                    long cc = bcol + wc2 * 64 + n * 32 + l31;
                    C[r * (long)N + cc] = acc[rb][n][i][j];
                }
#undef STAGE
}

// ---------------------------------------------------------------------------
extern "C" void kernel_launch(void* const* d_in, const int* in_sizes, int n_in,
                              void* d_out, int out_size, void* d_ws, size_t ws_size,
                              hipStream_t stream) {
    const float* x = (const float*)d_in[0];   // [B,T,D] fp32, M = B*T
    const float* w = (const float*)d_in[1];   // [O,D] fp32
    float* out = (float*)d_out;               // [M,O] fp32

    const int K = 4096;
    const long M = (long)in_sizes[0] / K;     // 8192
    const long N = (long)in_sizes[1] / K;     // 4096

    u16* Aq = (u16*)d_ws;                     // [M][K] fp8
    u16* Bq = Aq + (size_t)M * K / 2;         // [N][K] fp8
    float* Asc = (float*)(Bq + (size_t)N * K / 2);  // [32][M]
    float* Bsc = Asc + 32 * (size_t)M;              // [32][N]

    const long nA = M * 32, nTot = (M + N) * 32;
    quant_kernel<<<dim3((unsigned)((nTot / 2 + 3) / 4)), dim3(256), 0, stream>>>(
        x, w, (u32*)Aq, (u32*)Bq, Asc, Bsc, nA, nTot, M, N);

    static int smem_set = 0;
    if (!smem_set) {
        hipFuncSetAttribute((const void*)gemm_fp8,
                            hipFuncAttributeMaxDynamicSharedMemorySize, 33792);
        smem_set = 1;
    }
    dim3 grid((unsigned)((M / 128) * (N / 128)));
    gemm_fp8<<<grid, dim3(256), 33792, stream>>>(
        (const char*)Aq, (const char*)Bq, Asc, Bsc, out, (int)M, (int)N);
}

// Round 14
// 405.719 us; speedup vs baseline: 2.9004x; 2.9004x over previous
//
#include <hip/hip_runtime.h>

using u16 = unsigned short;
using u32 = unsigned int;
typedef int i32x4 __attribute__((ext_vector_type(4)));
typedef int i32x8 __attribute__((ext_vector_type(8)));
typedef float f32x4 __attribute__((ext_vector_type(4)));
typedef float f32x2 __attribute__((ext_vector_type(2)));
typedef float f32x16 __attribute__((ext_vector_type(16)));

#define SC1 0x7F7F7F7F  // e8m0 scale bytes = 2^0 = 1.0 (exact)

// ---------------------------------------------------------------------------
__device__ inline void async16(const void* g, void* l) {
    __builtin_amdgcn_global_load_lds(
        (__attribute__((address_space(1))) void*)(g),
        (__attribute__((address_space(3))) void*)(l),
        16, 0, 0);
}

__device__ inline i32x8 mk8(i32x4 lo, i32x4 hi) {
    return __builtin_shufflevector(lo, hi, 0, 1, 2, 3, 4, 5, 6, 7);
}

// ---------------------------------------------------------------------------
// Fused quantize, 2 blocks per wave (float4/lane): per-128-block
// s = amax * (1/448) (== amax/448 within 1 ulp), payload fp8 e4m3fn RNE of
// x * (448/amax). fp8 [R][K]; scales [K/128][R].
__global__ void quant_kernel(const float* __restrict__ x,
                             const float* __restrict__ w,
                             u32* __restrict__ Aq, u32* __restrict__ Bq,
                             float* __restrict__ Asc, float* __restrict__ Bsc,
                             long nA, long nTot, long MM, long NN) {
    long wv = (long)blockIdx.x * 4 + (threadIdx.x >> 6);
    int lane = threadIdx.x & 63;
    long b0 = wv * 2;
    if (b0 >= nTot) return;

    const float* in; u32* outq; float* outs; long R, id0;
    if (b0 < nA) { in = x; outq = Aq; outs = Asc; R = MM; id0 = b0; }
    else         { in = w; outq = Bq; outs = Bsc; R = NN; id0 = b0 - nA; }

    float4 v = reinterpret_cast<const float4*>(in)[id0 * 32 + lane];
    float a = fmaxf(fmaxf(fabsf(v.x), fabsf(v.y)), fmaxf(fabsf(v.z), fabsf(v.w)));
#pragma unroll
    for (int off = 16; off; off >>= 1) a = fmaxf(a, __shfl_xor(a, off));

    float s = a * (1.0f / 448.0f);
    float inv = 448.0f / a;

    float q0 = fminf(fmaxf(v.x * inv, -448.0f), 448.0f);
    float q1 = fminf(fmaxf(v.y * inv, -448.0f), 448.0f);
    float q2 = fminf(fmaxf(v.z * inv, -448.0f), 448.0f);
    float q3 = fminf(fmaxf(v.w * inv, -448.0f), 448.0f);

    int pk = __builtin_amdgcn_cvt_pk_fp8_f32(q0, q1, 0, false);
    pk = __builtin_amdgcn_cvt_pk_fp8_f32(q2, q3, pk, true);
    outq[id0 * 32 + lane] = (u32)pk;

    if ((lane & 31) == 0) {
        long b = id0 + (lane >> 5);
        outs[(b & 31) * R + (b >> 5)] = s;
    }
}

// ---------------------------------------------------------------------------
// fp8 block-scaled GEMM, 128x128 tile, 4 waves (2x2, wave tile 64x64),
// slab = K-block of 128. mfma_scale_f32_32x32x64_f8f6f4, HW scale 1.0;
// fp32 per-slab packed rescale (reference math, fp32 accumulate).
// Single-buffered LDS (33.8KB) + launch_bounds(256,3) -> 3 independent
// blocks/CU. R13's (256,4) forced a 128-total-reg cap (VGPR+AGPR unified;
// need ~180) -> 50-reg spill storm (WRITE 2.7GB). (256,3) caps ~170 (R10
// evidence: need 137, no spill); single-t COMPUTE cuts peak to ~155.
// Loop per slab: STAGE(kb) -> vmcnt(0)+barrier -> reads+compute -> barrier.
// LDS: A 16KB @0, B 16KB @16K, sa 512B @32K, sb 512B @32.5K.
// Swizzle byte^=(row&7)<<4 both-sides (128B rows, verified R6/R9).

#define SWZ(x) ((x) ^ ((((x) >> 7) & 7) << 4))

#define FENCE asm volatile("" ::: "memory");
#define BARRIER { __builtin_amdgcn_s_barrier(); FENCE }
#define VMC0 { asm volatile("s_waitcnt vmcnt(0)" ::: "memory"); }

__global__ __launch_bounds__(256, 3) void gemm_fp8(
    const char* __restrict__ Aq, const char* __restrict__ Bq,
    const float* __restrict__ AscaleG, const float* __restrict__ BscaleG,
    float* __restrict__ C, int M, int N) {
    extern __shared__ __align__(16) char smem[];
    const int KBYTES = 4096;

    const int tid = threadIdx.x;
    const int wid = tid >> 6;
    const int lane = tid & 63;
    const int l31 = lane & 31;
    const int lh = lane >> 5;
    const int wr2 = wid >> 1;          // 0..1 (M half)
    const int wc2 = wid & 1;           // 0..1 (N half)

    int nwg = gridDim.x, bid = blockIdx.x, swz = bid;
    if ((nwg & 7) == 0) swz = (bid & 7) * (nwg >> 3) + (bid >> 3);
    const int nbn = N >> 7;            // 32
    const long brow = (long)(swz / nbn) << 7;
    const long bcol = (long)(swz % nbn) << 7;

    const char* Abase = Aq + brow * KBYTES;
    const char* Bbase = Bq + bcol * KBYTES;

    // staging source offsets (inverse-swizzled); dloc = c*4096 + tid*16
    int aofs[4];
#pragma unroll
    for (int c = 0; c < 4; ++c) {
        int dloc = c * 4096 + tid * 16;
        int l = SWZ(dloc);
        aofs[c] = (l >> 7) * KBYTES + (l & 127);
    }

    // swizzled fragment column offsets (row&7 == lane&7 for all our rows)
    int cox[4];
#pragma unroll
    for (int kh = 0; kh < 2; ++kh)
#pragma unroll
        for (int hh = 0; hh < 2; ++hh)
            cox[kh * 2 + hh] =
                (((kh << 6) | (lh << 5) | (hh << 4)) ^ ((lane & 7) << 4));

    int arowb[2], brownn[2];
#pragma unroll
    for (int rb = 0; rb < 2; ++rb) arowb[rb] = (wr2 * 64 + rb * 32 + l31) << 7;
#pragma unroll
    for (int n = 0; n < 2; ++n) brownn[n] = (wc2 * 64 + n * 32 + l31) << 7;

#define STAGE(kb1) { \
    _Pragma("unroll") for (int c_ = 0; c_ < 4; ++c_) { \
        char* dA_ = smem + c_ * 4096 + wid * 1024; \
        async16(Abase + aofs[c_] + (long)(kb1) * 128, dA_); \
        async16(Bbase + aofs[c_] + (long)(kb1) * 128, dA_ + 16384); } \
    if (wid == 0 && lane < 32) \
        async16((const char*)AscaleG + ((long)(kb1) * M + brow) * 4 + lane * 16, \
                smem + 32768); \
    if (wid == 1 && lane < 32) \
        async16((const char*)BscaleG + ((long)(kb1) * N + bcol) * 4 + lane * 16, \
                smem + 33280); }

    f32x4 acc[2][2][4];
#pragma unroll
    for (int rb = 0; rb < 2; ++rb)
#pragma unroll
        for (int n = 0; n < 2; ++n)
#pragma unroll
            for (int i = 0; i < 4; ++i) acc[rb][n][i] = (f32x4){0.f, 0.f, 0.f, 0.f};

    const char* Ab = smem;
    const char* Bb = smem + 16384;
    const float* Sa = (const float*)(smem + 32768);
    const float* Sb = (const float*)(smem + 33280);

    for (int kb = 0; kb < 32; ++kb) {
        STAGE(kb);
        VMC0; BARRIER;

        i32x8 bfr[2][2];  // [n][kh]
#pragma unroll
        for (int n = 0; n < 2; ++n)
#pragma unroll
            for (int kh = 0; kh < 2; ++kh)
                bfr[n][kh] = mk8(*(const i32x4*)(Bb + brownn[n] + cox[kh * 2]),
                                 *(const i32x4*)(Bb + brownn[n] + cox[kh * 2 + 1]));
        float sbv[2];
#pragma unroll
        for (int n = 0; n < 2; ++n) sbv[n] = Sb[wc2 * 64 + n * 32 + l31];

#pragma unroll
        for (int rb = 0; rb < 2; ++rb) {
            i32x8 a0 = mk8(*(const i32x4*)(Ab + arowb[rb] + cox[0]),
                           *(const i32x4*)(Ab + arowb[rb] + cox[1]));
            i32x8 a1 = mk8(*(const i32x4*)(Ab + arowb[rb] + cox[2]),
                           *(const i32x4*)(Ab + arowb[rb] + cox[3]));
            f32x4 sa4[4];
#pragma unroll
            for (int i = 0; i < 4; ++i)
                sa4[i] = *(const f32x4*)(Sa + wr2 * 64 + rb * 32 + 4 * lh + 8 * i);
            // single-t: one f32x16 transient live at a time (reg-pressure cap)
#pragma unroll
            for (int n = 0; n < 2; ++n) {
                __builtin_amdgcn_s_setprio(1);
                f32x16 t = __builtin_amdgcn_mfma_scale_f32_32x32x64_f8f6f4(
                    a0, bfr[n][0], (f32x16)(0.f), 0, 0, 0, SC1, 0, SC1);
                t = __builtin_amdgcn_mfma_scale_f32_32x32x64_f8f6f4(
                    a1, bfr[n][1], t, 0, 0, 0, SC1, 0, SC1);
                __builtin_amdgcn_s_setprio(0);
#pragma unroll
                for (int i = 0; i < 4; ++i) {
                    f32x4 sp = sa4[i] * sbv[n];
                    f32x4 tv = (f32x4){t[i * 4], t[i * 4 + 1],
                                       t[i * 4 + 2], t[i * 4 + 3]};
                    acc[rb][n][i] = tv * sp + acc[rb][n][i];
                }
            }
        }

        BARRIER;  // WAR guard: all waves done reading before next STAGE
    }

    // epilogue: 32x32 C/D layout col = lane&31, row = (e&3)+8*(e>>2)+4*lh
#pragma unroll
    for (int rb = 0; rb < 2; ++rb)
#pragma unroll
        for (int n = 0; n < 2; ++n)
#pragma unroll
            for (int i = 0; i < 4; ++i)
#pragma unroll
                for (int j = 0; j < 4; ++j) {
                    long r = brow + wr2 * 64 + rb * 32 + j + 8 * i + 4 * lh;
                    long cc = bcol + wc2 * 64 + n * 32 + l31;
                    C[r * (long)N + cc] = acc[rb][n][i][j];
                }
#undef STAGE
}

// ---------------------------------------------------------------------------
extern "C" void kernel_launch(void* const* d_in, const int* in_sizes, int n_in,
                              void* d_out, int out_size, void* d_ws, size_t ws_size,
                              hipStream_t stream) {
    const float* x = (const float*)d_in[0];   // [B,T,D] fp32, M = B*T
    const float* w = (const float*)d_in[1];   // [O,D] fp32
    float* out = (float*)d_out;               // [M,O] fp32

    const int K = 4096;
    const long M = (long)in_sizes[0] / K;     // 8192
    const long N = (long)in_sizes[1] / K;     // 4096

    u16* Aq = (u16*)d_ws;                     // [M][K] fp8
    u16* Bq = Aq + (size_t)M * K / 2;         // [N][K] fp8
    float* Asc = (float*)(Bq + (size_t)N * K / 2);  // [32][M]
    float* Bsc = Asc + 32 * (size_t)M;              // [32][N]

    const long nA = M * 32, nTot = (M + N) * 32;
    quant_kernel<<<dim3((unsigned)((nTot / 2 + 3) / 4)), dim3(256), 0, stream>>>(
        x, w, (u32*)Aq, (u32*)Bq, Asc, Bsc, nA, nTot, M, N);

    static int smem_set = 0;
    if (!smem_set) {
        hipFuncSetAttribute((const void*)gemm_fp8,
                            hipFuncAttributeMaxDynamicSharedMemorySize, 33792);
        smem_set = 1;
    }
    dim3 grid((unsigned)((M / 128) * (N / 128)));
    gemm_fp8<<<grid, dim3(256), 33792, stream>>>(
        (const char*)Aq, (const char*)Bq, Asc, Bsc, out, (int)M, (int)N);
}

// Round 15
// 244.456 us; speedup vs baseline: 4.8138x; 1.6597x over previous
//
#include <hip/hip_runtime.h>

using u16 = unsigned short;
using u32 = unsigned int;
typedef int i32x4 __attribute__((ext_vector_type(4)));
typedef int i32x8 __attribute__((ext_vector_type(8)));
typedef float f32x4 __attribute__((ext_vector_type(4)));
typedef float f32x2 __attribute__((ext_vector_type(2)));
typedef float f32x16 __attribute__((ext_vector_type(16)));

#define SC1 0x7F7F7F7F  // e8m0 scale bytes = 2^0 = 1.0 (exact)

// ---------------------------------------------------------------------------
__device__ inline void async16(const void* g, void* l) {
    __builtin_amdgcn_global_load_lds(
        (__attribute__((address_space(1))) void*)(g),
        (__attribute__((address_space(3))) void*)(l),
        16, 0, 0);
}

__device__ inline i32x8 mk8(i32x4 lo, i32x4 hi) {
    return __builtin_shufflevector(lo, hi, 0, 1, 2, 3, 4, 5, 6, 7);
}

// ---------------------------------------------------------------------------
// Fused quantize, 2 blocks per wave (float4/lane): per-128-block
// s = amax * (1/448) (== amax/448 within 1 ulp), payload fp8 e4m3fn RNE of
// x * (448/amax). fp8 [R][K]; scales [K/128][R].
__global__ void quant_kernel(const float* __restrict__ x,
                             const float* __restrict__ w,
                             u32* __restrict__ Aq, u32* __restrict__ Bq,
                             float* __restrict__ Asc, float* __restrict__ Bsc,
                             long nA, long nTot, long MM, long NN) {
    long wv = (long)blockIdx.x * 4 + (threadIdx.x >> 6);
    int lane = threadIdx.x & 63;
    long b0 = wv * 2;
    if (b0 >= nTot) return;

    const float* in; u32* outq; float* outs; long R, id0;
    if (b0 < nA) { in = x; outq = Aq; outs = Asc; R = MM; id0 = b0; }
    else         { in = w; outq = Bq; outs = Bsc; R = NN; id0 = b0 - nA; }

    float4 v = reinterpret_cast<const float4*>(in)[id0 * 32 + lane];
    float a = fmaxf(fmaxf(fabsf(v.x), fabsf(v.y)), fmaxf(fabsf(v.z), fabsf(v.w)));
#pragma unroll
    for (int off = 16; off; off >>= 1) a = fmaxf(a, __shfl_xor(a, off));

    float s = a * (1.0f / 448.0f);
    float inv = 448.0f / a;

    float q0 = fminf(fmaxf(v.x * inv, -448.0f), 448.0f);
    float q1 = fminf(fmaxf(v.y * inv, -448.0f), 448.0f);
    float q2 = fminf(fmaxf(v.z * inv, -448.0f), 448.0f);
    float q3 = fminf(fmaxf(v.w * inv, -448.0f), 448.0f);

    int pk = __builtin_amdgcn_cvt_pk_fp8_f32(q0, q1, 0, false);
    pk = __builtin_amdgcn_cvt_pk_fp8_f32(q2, q3, pk, true);
    outq[id0 * 32 + lane] = (u32)pk;

    if ((lane & 31) == 0) {
        long b = id0 + (lane >> 5);
        outs[(b & 31) * R + (b >> 5)] = s;
    }
}

// ---------------------------------------------------------------------------
// fp8 block-scaled GEMM, 128x128 tile, 4 waves (2x2, wave tile 64x64),
// slab = K-block of 128. mfma_scale_f32_32x32x64_f8f6f4, HW scale 1.0;
// fp32 per-slab packed rescale (reference math, fp32 accumulate).
// MEASURED OPTIMUM (R12: gemm 197-199us). 2-phase dbuf loop: stage kb+1
// (issued BEFORE compute kb, so the end-of-slab vmcnt(0) drains loads that
// are ~1100 cyc old -> mostly landed), compute kb, vmcnt(0)+barrier.
// 2 blocks/CU. Failed alternatives (measured): per-phase pipelining (spills,
// R8/R13), single-buffer 3-4 blocks/CU (serializes, R14), smaller tile (R10),
// scale-path variants (R11).
// LDS: A dbuf 2x16KB @0, B dbuf 2x16KB @32K, sa 2x512B @64K, sb 2x512B @65K.
// Swizzle byte^=(row&7)<<4 both-sides (128B rows, verified R6/R9).

#define SWZ(x) ((x) ^ ((((x) >> 7) & 7) << 4))

#define FENCE asm volatile("" ::: "memory");
#define BARRIER { __builtin_amdgcn_s_barrier(); FENCE }
#define VMC0 { asm volatile("s_waitcnt vmcnt(0)" ::: "memory"); }

__global__ __launch_bounds__(256, 2) void gemm_fp8(
    const char* __restrict__ Aq, const char* __restrict__ Bq,
    const float* __restrict__ AscaleG, const float* __restrict__ BscaleG,
    float* __restrict__ C, int M, int N) {
    extern __shared__ __align__(16) char smem[];
    const int KBYTES = 4096;

    const int tid = threadIdx.x;
    const int wid = tid >> 6;
    const int lane = tid & 63;
    const int l31 = lane & 31;
    const int lh = lane >> 5;
    const int wr2 = wid >> 1;          // 0..1 (M half)
    const int wc2 = wid & 1;           // 0..1 (N half)

    int nwg = gridDim.x, bid = blockIdx.x, swz = bid;
    if ((nwg & 7) == 0) swz = (bid & 7) * (nwg >> 3) + (bid >> 3);
    const int nbn = N >> 7;            // 32
    const long brow = (long)(swz / nbn) << 7;
    const long bcol = (long)(swz % nbn) << 7;

    const char* Abase = Aq + brow * KBYTES;
    const char* Bbase = Bq + bcol * KBYTES;

    // staging source offsets (inverse-swizzled); dloc = c*4096 + tid*16
    int aofs[4];
#pragma unroll
    for (int c = 0; c < 4; ++c) {
        int dloc = c * 4096 + tid * 16;
        int l = SWZ(dloc);
        aofs[c] = (l >> 7) * KBYTES + (l & 127);
    }

    // swizzled fragment column offsets (row&7 == lane&7 for all our rows)
    int cox[4];
#pragma unroll
    for (int kh = 0; kh < 2; ++kh)
#pragma unroll
        for (int hh = 0; hh < 2; ++hh)
            cox[kh * 2 + hh] =
                (((kh << 6) | (lh << 5) | (hh << 4)) ^ ((lane & 7) << 4));

    int arowb[2], brownn[2];
#pragma unroll
    for (int rb = 0; rb < 2; ++rb) arowb[rb] = (wr2 * 64 + rb * 32 + l31) << 7;
#pragma unroll
    for (int n = 0; n < 2; ++n) brownn[n] = (wc2 * 64 + n * 32 + l31) << 7;

#define STAGE(kb1) { int bufb_ = (kb1) & 1; \
    _Pragma("unroll") for (int c_ = 0; c_ < 4; ++c_) { \
        char* dA_ = smem + bufb_ * 16384 + c_ * 4096 + wid * 1024; \
        async16(Abase + aofs[c_] + (long)(kb1) * 128, dA_); \
        async16(Bbase + aofs[c_] + (long)(kb1) * 128, dA_ + 32768); } \
    if (wid == 0 && lane < 32) \
        async16((const char*)AscaleG + ((long)(kb1) * M + brow) * 4 + lane * 16, \
                smem + 65536 + bufb_ * 512); \
    if (wid == 1 && lane < 32) \
        async16((const char*)BscaleG + ((long)(kb1) * N + bcol) * 4 + lane * 16, \
                smem + 66560 + bufb_ * 512); }

    f32x4 acc[2][2][4];
#pragma unroll
    for (int rb = 0; rb < 2; ++rb)
#pragma unroll
        for (int n = 0; n < 2; ++n)
#pragma unroll
            for (int i = 0; i < 4; ++i) acc[rb][n][i] = (f32x4){0.f, 0.f, 0.f, 0.f};

    // prologue
    STAGE(0);
    VMC0; BARRIER;

    for (int kb = 0; kb < 32; ++kb) {
        const int buf = kb & 1;
        if (kb < 31) STAGE(kb + 1);

        const char* Ab = smem + buf * 16384;
        const char* Bb = smem + 32768 + buf * 16384;
        const float* Sa = (const float*)(smem + 65536 + buf * 512);
        const float* Sb = (const float*)(smem + 66560 + buf * 512);

        i32x8 bfr[2][2];  // [n][kh]
#pragma unroll
        for (int n = 0; n < 2; ++n)
#pragma unroll
            for (int kh = 0; kh < 2; ++kh)
                bfr[n][kh] = mk8(*(const i32x4*)(Bb + brownn[n] + cox[kh * 2]),
                                 *(const i32x4*)(Bb + brownn[n] + cox[kh * 2 + 1]));
        float sbv[2];
#pragma unroll
        for (int n = 0; n < 2; ++n) sbv[n] = Sb[wc2 * 64 + n * 32 + l31];

#pragma unroll
        for (int rb = 0; rb < 2; ++rb) {
            i32x8 a0 = mk8(*(const i32x4*)(Ab + arowb[rb] + cox[0]),
                           *(const i32x4*)(Ab + arowb[rb] + cox[1]));
            i32x8 a1 = mk8(*(const i32x4*)(Ab + arowb[rb] + cox[2]),
                           *(const i32x4*)(Ab + arowb[rb] + cox[3]));
            f32x4 sa4[4];
#pragma unroll
            for (int i = 0; i < 4; ++i)
                sa4[i] = *(const f32x4*)(Sa + wr2 * 64 + rb * 32 + 4 * lh + 8 * i);
            __builtin_amdgcn_s_setprio(1);
            f32x16 t0 = __builtin_amdgcn_mfma_scale_f32_32x32x64_f8f6f4(
                a0, bfr[0][0], (f32x16)(0.f), 0, 0, 0, SC1, 0, SC1);
            t0 = __builtin_amdgcn_mfma_scale_f32_32x32x64_f8f6f4(
                a1, bfr[0][1], t0, 0, 0, 0, SC1, 0, SC1);
            f32x16 t1 = __builtin_amdgcn_mfma_scale_f32_32x32x64_f8f6f4(
                a0, bfr[1][0], (f32x16)(0.f), 0, 0, 0, SC1, 0, SC1);
            t1 = __builtin_amdgcn_mfma_scale_f32_32x32x64_f8f6f4(
                a1, bfr[1][1], t1, 0, 0, 0, SC1, 0, SC1);
            __builtin_amdgcn_s_setprio(0);
            // packed rescale: f32x4 -> v_pk_mul_f32 / v_pk_fma_f32
#pragma unroll
            for (int i = 0; i < 4; ++i) {
                f32x4 sp0 = sa4[i] * sbv[0];
                f32x4 sp1 = sa4[i] * sbv[1];
                f32x4 tv0 = (f32x4){t0[i * 4], t0[i * 4 + 1],
                                    t0[i * 4 + 2], t0[i * 4 + 3]};
                f32x4 tv1 = (f32x4){t1[i * 4], t1[i * 4 + 1],
                                    t1[i * 4 + 2], t1[i * 4 + 3]};
                acc[rb][0][i] = tv0 * sp0 + acc[rb][0][i];
                acc[rb][1][i] = tv1 * sp1 + acc[rb][1][i];
            }
        }

        VMC0; BARRIER;
    }

    // epilogue: 32x32 C/D layout col = lane&31, row = (e&3)+8*(e>>2)+4*lh
#pragma unroll
    for (int rb = 0; rb < 2; ++rb)
#pragma unroll
        for (int n = 0; n < 2; ++n)
#pragma unroll
            for (int i = 0; i < 4; ++i)
#pragma unroll
                for (int j = 0; j < 4; ++j) {
                    long r = brow + wr2 * 64 + rb * 32 + j + 8 * i + 4 * lh;
                    long cc = bcol + wc2 * 64 + n * 32 + l31;
                    C[r * (long)N + cc] = acc[rb][n][i][j];
                }
#undef STAGE
}

// ---------------------------------------------------------------------------
extern "C" void kernel_launch(void* const* d_in, const int* in_sizes, int n_in,
                              void* d_out, int out_size, void* d_ws, size_t ws_size,
                              hipStream_t stream) {
    const float* x = (const float*)d_in[0];   // [B,T,D] fp32, M = B*T
    const float* w = (const float*)d_in[1];   // [O,D] fp32
    float* out = (float*)d_out;               // [M,O] fp32

    const int K = 4096;
    const long M = (long)in_sizes[0] / K;     // 8192
    const long N = (long)in_sizes[1] / K;     // 4096

    u16* Aq = (u16*)d_ws;                     // [M][K] fp8
    u16* Bq = Aq + (size_t)M * K / 2;         // [N][K] fp8
    float* Asc = (float*)(Bq + (size_t)N * K / 2);  // [32][M]
    float* Bsc = Asc + 32 * (size_t)M;              // [32][N]

    const long nA = M * 32, nTot = (M + N) * 32;
    quant_kernel<<<dim3((unsigned)((nTot / 2 + 3) / 4)), dim3(256), 0, stream>>>(
        x, w, (u32*)Aq, (u32*)Bq, Asc, Bsc, nA, nTot, M, N);

    static int smem_set = 0;
    if (!smem_set) {
        hipFuncSetAttribute((const void*)gemm_fp8,
                            hipFuncAttributeMaxDynamicSharedMemorySize, 67584);
        smem_set = 1;
    }
    dim3 grid((unsigned)((M / 128) * (N / 128)));
    gemm_fp8<<<grid, dim3(256), 67584, stream>>>(
        (const char*)Aq, (const char*)Bq, Asc, Bsc, out, (int)M, (int)N);
}

// Round 16
// 233.235 us; speedup vs baseline: 5.0454x; 1.0481x over previous
//
#include <hip/hip_runtime.h>

using u16 = unsigned short;
using u32 = unsigned int;
typedef int i32x4 __attribute__((ext_vector_type(4)));
typedef int i32x8 __attribute__((ext_vector_type(8)));
typedef float f32x4 __attribute__((ext_vector_type(4)));
typedef float f32x2 __attribute__((ext_vector_type(2)));
typedef float f32x16 __attribute__((ext_vector_type(16)));

#define SC1 0x7F7F7F7F  // e8m0 scale bytes = 2^0 = 1.0 (exact)

// ---------------------------------------------------------------------------
__device__ inline void async16(const void* g, void* l) {
    __builtin_amdgcn_global_load_lds(
        (__attribute__((address_space(1))) void*)(g),
        (__attribute__((address_space(3))) void*)(l),
        16, 0, 0);
}

__device__ inline i32x8 mk8(i32x4 lo, i32x4 hi) {
    return __builtin_shufflevector(lo, hi, 0, 1, 2, 3, 4, 5, 6, 7);
}

// ---------------------------------------------------------------------------
// Fused quantize, 2 blocks per wave (float4/lane): per-128-block
// s = amax * (1/448) (== amax/448 within 1 ulp), payload fp8 e4m3fn RNE of
// x * (448/amax). fp8 [R][K]; scales [K/128][R].
__global__ void quant_kernel(const float* __restrict__ x,
                             const float* __restrict__ w,
                             u32* __restrict__ Aq, u32* __restrict__ Bq,
                             float* __restrict__ Asc, float* __restrict__ Bsc,
                             long nA, long nTot, long MM, long NN) {
    long wv = (long)blockIdx.x * 4 + (threadIdx.x >> 6);
    int lane = threadIdx.x & 63;
    long b0 = wv * 2;
    if (b0 >= nTot) return;

    const float* in; u32* outq; float* outs; long R, id0;
    if (b0 < nA) { in = x; outq = Aq; outs = Asc; R = MM; id0 = b0; }
    else         { in = w; outq = Bq; outs = Bsc; R = NN; id0 = b0 - nA; }

    float4 v = reinterpret_cast<const float4*>(in)[id0 * 32 + lane];
    float a = fmaxf(fmaxf(fabsf(v.x), fabsf(v.y)), fmaxf(fabsf(v.z), fabsf(v.w)));
#pragma unroll
    for (int off = 16; off; off >>= 1) a = fmaxf(a, __shfl_xor(a, off));

    float s = a * (1.0f / 448.0f);
    float inv = 448.0f / a;

    float q0 = fminf(fmaxf(v.x * inv, -448.0f), 448.0f);
    float q1 = fminf(fmaxf(v.y * inv, -448.0f), 448.0f);
    float q2 = fminf(fmaxf(v.z * inv, -448.0f), 448.0f);
    float q3 = fminf(fmaxf(v.w * inv, -448.0f), 448.0f);

    int pk = __builtin_amdgcn_cvt_pk_fp8_f32(q0, q1, 0, false);
    pk = __builtin_amdgcn_cvt_pk_fp8_f32(q2, q3, pk, true);
    outq[id0 * 32 + lane] = (u32)pk;

    if ((lane & 31) == 0) {
        long b = id0 + (lane >> 5);
        outs[(b & 31) * R + (b >> 5)] = s;
    }
}

// ---------------------------------------------------------------------------
// fp8 block-scaled GEMM, 128x128 tile, 4 waves (2x2, wave tile 64x64),
// slab = K-block of 128. mfma_scale_f32_32x32x64_f8f6f4, HW scale 1.0;
// fp32 per-slab packed rescale (reference math, fp32 accumulate).
// BEST-TIMED CONFIG (R11 total = 237.0us vs R12/R15 = 244.6):
//  - B-scales: per-lane direct global loads (L2-resident, compiler-counted
//    vmcnt hides them under slab compute)
//  - A-scales: staged by ALL waves (duplicate same-data DMA, benign)
//  - packed f32x4 rescale (A/B'd neutral R9->R12)
// 2-phase dbuf loop: stage kb+1 before compute kb, vmcnt(0)+barrier.
// 2 blocks/CU. Measured-worse alternatives: 4-phase pipeline (spills),
// single-buffer 3-4 blocks/CU (serializes), 64-wide tile (traffic),
// bf16 8-phase 256^2 (1090 TF < fp8's 1390).
// LDS: A dbuf 2x16KB @0, B dbuf 2x16KB @32K, sa 2x512B @64K = 65.5KB.
// Swizzle byte^=(row&7)<<4 both-sides (128B rows, verified R6/R9).

#define SWZ(x) ((x) ^ ((((x) >> 7) & 7) << 4))

#define FENCE asm volatile("" ::: "memory");
#define BARRIER { __builtin_amdgcn_s_barrier(); FENCE }
#define VMC0 { asm volatile("s_waitcnt vmcnt(0)" ::: "memory"); }

__global__ __launch_bounds__(256, 2) void gemm_fp8(
    const char* __restrict__ Aq, const char* __restrict__ Bq,
    const float* __restrict__ AscaleG, const float* __restrict__ BscaleG,
    float* __restrict__ C, int M, int N) {
    extern __shared__ __align__(16) char smem[];
    const int KBYTES = 4096;

    const int tid = threadIdx.x;
    const int wid = tid >> 6;
    const int lane = tid & 63;
    const int l31 = lane & 31;
    const int lh = lane >> 5;
    const int wr2 = wid >> 1;          // 0..1 (M half)
    const int wc2 = wid & 1;           // 0..1 (N half)

    int nwg = gridDim.x, bid = blockIdx.x, swz = bid;
    if ((nwg & 7) == 0) swz = (bid & 7) * (nwg >> 3) + (bid >> 3);
    const int nbn = N >> 7;            // 32
    const long brow = (long)(swz / nbn) << 7;
    const long bcol = (long)(swz % nbn) << 7;

    const char* Abase = Aq + brow * KBYTES;
    const char* Bbase = Bq + bcol * KBYTES;

    // staging source offsets (inverse-swizzled); dloc = c*4096 + tid*16
    int aofs[4];
#pragma unroll
    for (int c = 0; c < 4; ++c) {
        int dloc = c * 4096 + tid * 16;
        int l = SWZ(dloc);
        aofs[c] = (l >> 7) * KBYTES + (l & 127);
    }

    // swizzled fragment column offsets (row&7 == lane&7 for all our rows)
    int cox[4];
#pragma unroll
    for (int kh = 0; kh < 2; ++kh)
#pragma unroll
        for (int hh = 0; hh < 2; ++hh)
            cox[kh * 2 + hh] =
                (((kh << 6) | (lh << 5) | (hh << 4)) ^ ((lane & 7) << 4));

    int arowb[2], brownn[2];
#pragma unroll
    for (int rb = 0; rb < 2; ++rb) arowb[rb] = (wr2 * 64 + rb * 32 + l31) << 7;
#pragma unroll
    for (int n = 0; n < 2; ++n) brownn[n] = (wc2 * 64 + n * 32 + l31) << 7;

#define STAGE(kb1) { int bufb_ = (kb1) & 1; \
    _Pragma("unroll") for (int c_ = 0; c_ < 4; ++c_) { \
        char* dA_ = smem + bufb_ * 16384 + c_ * 4096 + wid * 1024; \
        async16(Abase + aofs[c_] + (long)(kb1) * 128, dA_); \
        async16(Bbase + aofs[c_] + (long)(kb1) * 128, dA_ + 32768); } \
    if (lane < 32) \
        async16((const char*)AscaleG + ((long)(kb1) * M + brow) * 4 + lane * 16, \
                smem + 65536 + bufb_ * 512); }

    f32x4 acc[2][2][4];
#pragma unroll
    for (int rb = 0; rb < 2; ++rb)
#pragma unroll
        for (int n = 0; n < 2; ++n)
#pragma unroll
            for (int i = 0; i < 4; ++i) acc[rb][n][i] = (f32x4){0.f, 0.f, 0.f, 0.f};

    // prologue
    STAGE(0);
    VMC0; BARRIER;

    for (int kb = 0; kb < 32; ++kb) {
        const int buf = kb & 1;

        // B-scales for THIS slab: per-lane direct global loads (coalesced
        // 128B, L2-resident); latency hides under the slab's ds_reads/MFMA.
        const float* SbG = BscaleG + (long)kb * N + bcol;
        float sbv0 = SbG[wc2 * 64 + l31];
        float sbv1 = SbG[wc2 * 64 + 32 + l31];

        if (kb < 31) STAGE(kb + 1);

        const char* Ab = smem + buf * 16384;
        const char* Bb = smem + 32768 + buf * 16384;
        const float* Sa = (const float*)(smem + 65536 + buf * 512);

        i32x8 bfr[2][2];  // [n][kh]
#pragma unroll
        for (int n = 0; n < 2; ++n)
#pragma unroll
            for (int kh = 0; kh < 2; ++kh)
                bfr[n][kh] = mk8(*(const i32x4*)(Bb + brownn[n] + cox[kh * 2]),
                                 *(const i32x4*)(Bb + brownn[n] + cox[kh * 2 + 1]));

#pragma unroll
        for (int rb = 0; rb < 2; ++rb) {
            i32x8 a0 = mk8(*(const i32x4*)(Ab + arowb[rb] + cox[0]),
                           *(const i32x4*)(Ab + arowb[rb] + cox[1]));
            i32x8 a1 = mk8(*(const i32x4*)(Ab + arowb[rb] + cox[2]),
                           *(const i32x4*)(Ab + arowb[rb] + cox[3]));
            f32x4 sa4[4];
#pragma unroll
            for (int i = 0; i < 4; ++i)
                sa4[i] = *(const f32x4*)(Sa + wr2 * 64 + rb * 32 + 4 * lh + 8 * i);
            __builtin_amdgcn_s_setprio(1);
            f32x16 t0 = __builtin_amdgcn_mfma_scale_f32_32x32x64_f8f6f4(
                a0, bfr[0][0], (f32x16)(0.f), 0, 0, 0, SC1, 0, SC1);
            t0 = __builtin_amdgcn_mfma_scale_f32_32x32x64_f8f6f4(
                a1, bfr[0][1], t0, 0, 0, 0, SC1, 0, SC1);
            f32x16 t1 = __builtin_amdgcn_mfma_scale_f32_32x32x64_f8f6f4(
                a0, bfr[1][0], (f32x16)(0.f), 0, 0, 0, SC1, 0, SC1);
            t1 = __builtin_amdgcn_mfma_scale_f32_32x32x64_f8f6f4(
                a1, bfr[1][1], t1, 0, 0, 0, SC1, 0, SC1);
            __builtin_amdgcn_s_setprio(0);
            // packed rescale: f32x4 -> v_pk_mul_f32 / v_pk_fma_f32
#pragma unroll
            for (int i = 0; i < 4; ++i) {
                f32x4 sp0 = sa4[i] * sbv0;
                f32x4 sp1 = sa4[i] * sbv1;
                f32x4 tv0 = (f32x4){t0[i * 4], t0[i * 4 + 1],
                                    t0[i * 4 + 2], t0[i * 4 + 3]};
                f32x4 tv1 = (f32x4){t1[i * 4], t1[i * 4 + 1],
                                    t1[i * 4 + 2], t1[i * 4 + 3]};
                acc[rb][0][i] = tv0 * sp0 + acc[rb][0][i];
                acc[rb][1][i] = tv1 * sp1 + acc[rb][1][i];
            }
        }

        VMC0; BARRIER;
    }

    // epilogue: 32x32 C/D layout col = lane&31, row = (e&3)+8*(e>>2)+4*lh
#pragma unroll
    for (int rb = 0; rb < 2; ++rb)
#pragma unroll
        for (int n = 0; n < 2; ++n)
#pragma unroll
            for (int i = 0; i < 4; ++i)
#pragma unroll
                for (int j = 0; j < 4; ++j) {
                    long r = brow + wr2 * 64 + rb * 32 + j + 8 * i + 4 * lh;
                    long cc = bcol + wc2 * 64 + n * 32 + l31;
                    C[r * (long)N + cc] = acc[rb][n][i][j];
                }
#undef STAGE
}

// ---------------------------------------------------------------------------
extern "C" void kernel_launch(void* const* d_in, const int* in_sizes, int n_in,
                              void* d_out, int out_size, void* d_ws, size_t ws_size,
                              hipStream_t stream) {
    const float* x = (const float*)d_in[0];   // [B,T,D] fp32, M = B*T
    const float* w = (const float*)d_in[1];   // [O,D] fp32
    float* out = (float*)d_out;               // [M,O] fp32

    const int K = 4096;
    const long M = (long)in_sizes[0] / K;     // 8192
    const long N = (long)in_sizes[1] / K;     // 4096

    u16* Aq = (u16*)d_ws;                     // [M][K] fp8
    u16* Bq = Aq + (size_t)M * K / 2;         // [N][K] fp8
    float* Asc = (float*)(Bq + (size_t)N * K / 2);  // [32][M]
    float* Bsc = Asc + 32 * (size_t)M;              // [32][N]

    const long nA = M * 32, nTot = (M + N) * 32;
    quant_kernel<<<dim3((unsigned)((nTot / 2 + 3) / 4)), dim3(256), 0, stream>>>(
        x, w, (u32*)Aq, (u32*)Bq, Asc, Bsc, nA, nTot, M, N);

    static int smem_set = 0;
    if (!smem_set) {
        hipFuncSetAttribute((const void*)gemm_fp8,
                            hipFuncAttributeMaxDynamicSharedMemorySize, 66560);
        smem_set = 1;
    }
    dim3 grid((unsigned)((M / 128) * (N / 128)));
    gemm_fp8<<<grid, dim3(256), 66560, stream>>>(
        (const char*)Aq, (const char*)Bq, Asc, Bsc, out, (int)M, (int)N);
}